// Round 8
// baseline (412.325 us; speedup 1.0000x reference)
//
#include <hip/hip_runtime.h>
#include <hip/hip_bf16.h>

#define DEV __device__ __forceinline__

typedef __attribute__((ext_vector_type(8))) short bf16x8;
typedef __attribute__((ext_vector_type(8))) unsigned short u16x8;
typedef __attribute__((ext_vector_type(4))) float f32x4;

DEV unsigned short f2bf(float f) {
  return __builtin_bit_cast(unsigned short, __float2bfloat16(f));
}
DEV float bf2f(unsigned short h) { return __uint_as_float(((unsigned int)h) << 16); }

// LDS swizzle for BK=64 tiles (128B rows): XOR 16B-slot with (row&7).
DEV int swz(int row, int byteoff) { return row * 128 + (byteoff ^ ((row & 7) << 4)); }

// ---------------------------------------------------------------- GEMM (LN-fusing, fp32-weight-staging)
// Y[m,n] = act( X'[m,:]·W[n,:] + bias[n] [+ res'[m,n]] )
// A path: ALN -> LN(Xf) at staging; AF32 -> convert Xf; else Xb bf16.
// B path: WF32 -> convert Wf fp32 at staging; else Wb bf16.
// res' = RES ? (RLN ? LN(resf) : resf) : 0  (stride 512). STATS: per-row atomics.
// 256 threads, 4 waves 2x2; BK=64 reg-staged dbuf pipeline (validated R1).
template <int BM, int BN, int ALN, int AF32, int WF32, int RES, int RLN, int ACT, int STATS,
          int OUTF32, int OUTBF>
__global__ __launch_bounds__(256) void gemm2_kernel(
    const unsigned short* __restrict__ Xb, const float* __restrict__ Xf,
    const float* __restrict__ sA, const float* __restrict__ gA, const float* __restrict__ bA,
    const unsigned short* __restrict__ Wb, const float* __restrict__ Wf,
    const float* __restrict__ bias,
    const float* __restrict__ resf, const float* __restrict__ sR,
    const float* __restrict__ gR, const float* __restrict__ bR,
    float* __restrict__ Yf, unsigned short* __restrict__ Ybf, float* __restrict__ stats,
    int M, int N, int K, long xbs, long wbs, long bbs, long ybs) {
  constexpr int CA = BM / 32, CB = BN / 32;
  constexpr int ABY = BM * 64 * 2, BBY = BN * 64 * 2;
  constexpr int MI = BM / 32, NI = BN / 32;
  __shared__ __align__(16) char Asb[2 * ABY];
  __shared__ __align__(16) char Bsb[2 * BBY];
  const int t = threadIdx.x;
  const int bn = blockIdx.x, bm = blockIdx.y, bz = blockIdx.z;
  const int lane = t & 63, wv = t >> 6, wr = wv >> 1, wc = wv & 1;

  int rowA[CA], slotA[CA], rowB[CB], slotB[CB];
#pragma unroll
  for (int c = 0; c < CA; ++c) { int id = c * 256 + t; rowA[c] = id >> 3; slotA[c] = id & 7; }
#pragma unroll
  for (int c = 0; c < CB; ++c) { int id = c * 256 + t; rowB[c] = id >> 3; slotB[c] = id & 7; }

  float mA[CA], iA[CA];
  if (ALN) {
#pragma unroll
    for (int c = 0; c < CA; ++c) {
      const int gm = bm * BM + rowA[c];
      const float s = sA[2 * gm], q = sA[2 * gm + 1];
      mA[c] = s * (1.f / 512.f);
      iA[c] = rsqrtf(q * (1.f / 512.f) - mA[c] * mA[c] + 1e-5f);
    }
  }

  f32x4 acc[MI][NI];
#pragma unroll
  for (int mi = 0; mi < MI; ++mi)
#pragma unroll
    for (int ni = 0; ni < NI; ++ni) acc[mi][ni] = f32x4{0.f, 0.f, 0.f, 0.f};

  u16x8 ra[CA], rb[CB];
  f32x4 raf[CA][2], rbf[CB][2];
  auto load = [&](int kt) {
#pragma unroll
    for (int c = 0; c < CA; ++c) {
      if (ALN || AF32) {
        const float* p = Xf + (long)(bm * BM + rowA[c]) * K + kt + slotA[c] * 8;
        raf[c][0] = *(const f32x4*)p;
        raf[c][1] = *(const f32x4*)(p + 4);
      } else {
        ra[c] = *(const u16x8*)(Xb + (long)bz * xbs + (long)(bm * BM + rowA[c]) * K + kt + slotA[c] * 8);
      }
    }
#pragma unroll
    for (int c = 0; c < CB; ++c) {
      if (WF32) {
        const float* p = Wf + (long)bz * wbs + (long)(bn * BN + rowB[c]) * K + kt + slotB[c] * 8;
        rbf[c][0] = *(const f32x4*)p;
        rbf[c][1] = *(const f32x4*)(p + 4);
      } else {
        rb[c] = *(const u16x8*)(Wb + (long)bz * wbs + (long)(bn * BN + rowB[c]) * K + kt + slotB[c] * 8);
      }
    }
  };
  auto store = [&](int cur, int kt) {
#pragma unroll
    for (int c = 0; c < CA; ++c) {
      u16x8 o;
      if (ALN) {
        const int col = kt + slotA[c] * 8;
        f32x4 g0 = *(const f32x4*)(gA + col), g1 = *(const f32x4*)(gA + col + 4);
        f32x4 b0 = *(const f32x4*)(bA + col), b1 = *(const f32x4*)(bA + col + 4);
#pragma unroll
        for (int j = 0; j < 4; ++j) o[j] = f2bf((raf[c][0][j] - mA[c]) * iA[c] * g0[j] + b0[j]);
#pragma unroll
        for (int j = 0; j < 4; ++j) o[4 + j] = f2bf((raf[c][1][j] - mA[c]) * iA[c] * g1[j] + b1[j]);
      } else if (AF32) {
#pragma unroll
        for (int j = 0; j < 4; ++j) o[j] = f2bf(raf[c][0][j]);
#pragma unroll
        for (int j = 0; j < 4; ++j) o[4 + j] = f2bf(raf[c][1][j]);
      } else {
        o = ra[c];
      }
      *(u16x8*)(Asb + cur * ABY + swz(rowA[c], slotA[c] * 16)) = o;
    }
#pragma unroll
    for (int c = 0; c < CB; ++c) {
      u16x8 o;
      if (WF32) {
#pragma unroll
        for (int j = 0; j < 4; ++j) o[j] = f2bf(rbf[c][0][j]);
#pragma unroll
        for (int j = 0; j < 4; ++j) o[4 + j] = f2bf(rbf[c][1][j]);
      } else {
        o = rb[c];
      }
      *(u16x8*)(Bsb + cur * BBY + swz(rowB[c], slotB[c] * 16)) = o;
    }
  };

  const int NT = K >> 6;
  load(0);
  store(0, 0);
  load(64);
  __syncthreads();
  for (int ki = 0; ki < NT; ++ki) {
    const int cur = ki & 1;
    if (ki + 1 < NT) store(cur ^ 1, (ki + 1) << 6);
    if (ki + 2 < NT) load((ki + 2) << 6);
#pragma unroll
    for (int kk = 0; kk < 2; ++kk) {
      const int kb = kk * 64 + ((lane >> 4) << 4);
      bf16x8 af[MI], bfv[NI];
#pragma unroll
      for (int mi = 0; mi < MI; ++mi)
        af[mi] = *(const bf16x8*)(Asb + cur * ABY + swz(wr * (BM / 2) + mi * 16 + (lane & 15), kb));
#pragma unroll
      for (int ni = 0; ni < NI; ++ni)
        bfv[ni] = *(const bf16x8*)(Bsb + cur * BBY + swz(wc * (BN / 2) + ni * 16 + (lane & 15), kb));
#pragma unroll
      for (int mi = 0; mi < MI; ++mi)
#pragma unroll
        for (int ni = 0; ni < NI; ++ni)
          acc[mi][ni] = __builtin_amdgcn_mfma_f32_16x16x32_bf16(af[mi], bfv[ni], acc[mi][ni], 0, 0, 0);
    }
    __syncthreads();
  }

  // epilogue
#pragma unroll
  for (int mi = 0; mi < MI; ++mi) {
#pragma unroll
    for (int rr = 0; rr < 4; ++rr) {
      const int gm = bm * BM + wr * (BM / 2) + mi * 16 + ((lane >> 4) << 2) + rr;
      float mR, iR;
      if (RES && RLN) {
        const float s = sR[2 * gm], q = sR[2 * gm + 1];
        mR = s * (1.f / 512.f);
        iR = rsqrtf(q * (1.f / 512.f) - mR * mR + 1e-5f);
      }
      float srow = 0.f, qrow = 0.f;
#pragma unroll
      for (int ni = 0; ni < NI; ++ni) {
        const int gn = bn * BN + wc * (BN / 2) + ni * 16 + (lane & 15);
        float v = acc[mi][ni][rr] + bias[(long)bz * bbs + gn];
        if (RES) {
          float r = resf[(long)gm * 512 + gn];
          if (RLN) r = (r - mR) * iR * gR[gn] + bR[gn];
          v += r;
        }
        if (ACT) v = fmaxf(v, 0.f);
        if (STATS) { srow += v; qrow += v * v; }
        const long o = (long)bz * ybs + (long)gm * N + gn;
        if (OUTF32) Yf[o] = v;
        if (OUTBF) Ybf[o] = f2bf(v);
      }
      if (STATS) {
#pragma unroll
        for (int msk = 1; msk < 16; msk <<= 1) {
          srow += __shfl_xor(srow, msk, 64);
          qrow += __shfl_xor(qrow, msk, 64);
        }
        if ((lane & 15) == 0) {
          atomicAdd(&stats[2 * gm], srow);
          atomicAdd(&stats[2 * gm + 1], qrow);
        }
      }
    }
  }
}

// ---------------------------------------------------------------- attention + outproj fused
// One block per s (128 blocks, 512 threads). qkv t1:(1024,1536) bf16.
// Phase A: scores+softmax+PV -> bf16 A-tile (16x512 LDS, rows 8..15 zero).
// Phase B: outproj = A x W^T (W fp32 512x512 staged 128x64 dbuf), + bias + residual
// (optional LN via sR/gR/bR), writes t2a fp32 + per-row LN stats (plain stores).
template <int RLN>
__global__ __launch_bounds__(512) void attnop_kernel(
    const unsigned short* __restrict__ qkv, const float* __restrict__ Wf,
    const float* __restrict__ bias, const float* __restrict__ resf,
    const float* __restrict__ sR, const float* __restrict__ gR, const float* __restrict__ bR,
    float* __restrict__ t2a, float* __restrict__ stats) {
  __shared__ float P[512];
  __shared__ float Sred[8][16][2];
  __shared__ __align__(16) char As[16 * 1024];
  __shared__ __align__(16) char Bs[2 * 128 * 128];
  const int s = blockIdx.x;
  const int t = threadIdx.x;
  const int lane = t & 63, w = t >> 6;

  // prefetch first W tile while attention runs
  int rowB[2], slotB[2];
#pragma unroll
  for (int c = 0; c < 2; ++c) { int id = c * 512 + t; rowB[c] = id >> 3; slotB[c] = id & 7; }
  f32x4 rbf[2][2];
  auto loadB = [&](int tau) {
    const int nb = (tau >> 3) * 128, kt = (tau & 7) * 64;
#pragma unroll
    for (int c = 0; c < 2; ++c) {
      const float* p = Wf + (long)(nb + rowB[c]) * 512 + kt + slotB[c] * 8;
      rbf[c][0] = *(const f32x4*)p;
      rbf[c][1] = *(const f32x4*)(p + 4);
    }
  };
  auto storeB = [&](int cur) {
#pragma unroll
    for (int c = 0; c < 2; ++c) {
      u16x8 o;
#pragma unroll
      for (int j = 0; j < 4; ++j) o[j] = f2bf(rbf[c][0][j]);
#pragma unroll
      for (int j = 0; j < 4; ++j) o[4 + j] = f2bf(rbf[c][1][j]);
      *(u16x8*)(Bs + cur * 16384 + swz(rowB[c], slotB[c] * 16)) = o;
    }
  };
  loadB(0);

  // zero A-tile pad rows 8..15 (8KB = 512 threads x 16B)
  *(f32x4*)(As + 8 * 1024 + t * 16) = f32x4{0.f, 0.f, 0.f, 0.f};

  // phase A: scores (one (h,l,m) per thread)
  {
    const int h = t >> 6, l = (t >> 3) & 7, m = t & 7;
    const unsigned short* qp = qkv + (long)(l * 128 + s) * 1536 + h * 64;
    const unsigned short* kp = qkv + (long)(m * 128 + s) * 1536 + 512 + h * 64;
    float acc = 0.f;
#pragma unroll
    for (int c = 0; c < 64; c += 8) {
      u16x8 q8 = *(const u16x8*)(qp + c);
      u16x8 k8 = *(const u16x8*)(kp + c);
#pragma unroll
      for (int j = 0; j < 8; ++j) acc += bf2f(q8[j]) * bf2f(k8[j]);
    }
    P[t] = acc * 0.125f;  // 1/sqrt(64)
  }
  __syncthreads();
  if (t < 64) {  // softmax rows (h,l)
    const int base = t * 8;
    float mx = -1e30f;
#pragma unroll
    for (int m = 0; m < 8; ++m) mx = fmaxf(mx, P[base + m]);
    float e[8], sum = 0.f;
#pragma unroll
    for (int m = 0; m < 8; ++m) { e[m] = expf(P[base + m] - mx); sum += e[m]; }
    const float inv = 1.f / sum;
#pragma unroll
    for (int m = 0; m < 8; ++m) P[base + m] = e[m] * inv;
  }
  __syncthreads();
  // PV -> As (row l, 8 cols per thread)
  {
    const int l = t >> 6, c0 = lane * 8, h = c0 >> 6;
    float o[8] = {0.f, 0.f, 0.f, 0.f, 0.f, 0.f, 0.f, 0.f};
#pragma unroll
    for (int m = 0; m < 8; ++m) {
      const float p = P[h * 64 + l * 8 + m];
      u16x8 v8 = *(const u16x8*)(qkv + (long)(m * 128 + s) * 1536 + 1024 + c0);
#pragma unroll
      for (int j = 0; j < 8; ++j) o[j] += p * bf2f(v8[j]);
    }
    u16x8 pk;
#pragma unroll
    for (int j = 0; j < 8; ++j) pk[j] = f2bf(o[j]);
    *(u16x8*)(As + l * 1024 + ((c0 * 2) ^ ((l & 7) << 4))) = pk;
  }
  __syncthreads();

  // phase B: outproj, 32 tiles tau = nc*8 + ks (nc: 128-col n-chunk, ks: 64-elem k-step)
  f32x4 acc[4] = {};
  storeB(0);
  loadB(1);
  __syncthreads();
  for (int tau = 0; tau < 32; ++tau) {
    const int cur = tau & 1;
    if (tau + 1 < 32) storeB(cur ^ 1);
    if (tau + 2 < 32) loadB(tau + 2);
    const int nc = tau >> 3;
#pragma unroll
    for (int kk = 0; kk < 2; ++kk) {
      const int arow = lane & 15;
      const int kbyte = ((tau & 7) << 7) + (kk << 6) + ((lane >> 4) << 4);
      bf16x8 af = *(const bf16x8*)(As + arow * 1024 + (kbyte ^ ((arow & 7) << 4)));
      bf16x8 bv = *(const bf16x8*)(Bs + cur * 16384 +
                                   swz(w * 16 + (lane & 15), (kk << 6) + ((lane >> 4) << 4)));
      acc[nc] = __builtin_amdgcn_mfma_f32_16x16x32_bf16(af, bv, acc[nc], 0, 0, 0);
    }
    __syncthreads();
  }

  // epilogue: rows l = (lane>>4)*4+rr (valid l<8), col n = nc*128 + w*16 + (lane&15)
#pragma unroll
  for (int rr = 0; rr < 4; ++rr) {
    const int l = ((lane >> 4) << 2) + rr;
    if (l < 8) {
      const int g = l * 128 + s;
      float mR, iR;
      if (RLN) {
        const float sv = sR[2 * g], qv = sR[2 * g + 1];
        mR = sv * (1.f / 512.f);
        iR = rsqrtf(qv * (1.f / 512.f) - mR * mR + 1e-5f);
      }
      float sr = 0.f, qr = 0.f;
#pragma unroll
      for (int nc = 0; nc < 4; ++nc) {
        const int n = nc * 128 + w * 16 + (lane & 15);
        float v = acc[nc][rr] + bias[n];
        float r = resf[(long)g * 512 + n];
        if (RLN) r = (r - mR) * iR * gR[n] + bR[n];
        v += r;
        sr += v; qr += v * v;
        t2a[(long)g * 512 + n] = v;
      }
#pragma unroll
      for (int msk = 1; msk < 16; msk <<= 1) {
        sr += __shfl_xor(sr, msk, 64);
        qr += __shfl_xor(qr, msk, 64);
      }
      if ((lane & 15) == 0) { Sred[w][l][0] = sr; Sred[w][l][1] = qr; }
    }
  }
  __syncthreads();
  if (t < 8) {
    float S = 0.f, Q = 0.f;
#pragma unroll
    for (int ww = 0; ww < 8; ++ww) { S += Sred[ww][t][0]; Q += Sred[ww][t][1]; }
    const int g = t * 128 + s;
    stats[2 * g] = S;
    stats[2 * g + 1] = Q;
  }
}

// ---------------------------------------------------------------- last LN2 -> FLN chained
__global__ __launch_bounds__(256) void lastln_kernel(const float* __restrict__ t2,
                                                     const float* __restrict__ S,
                                                     const float* __restrict__ g2,
                                                     const float* __restrict__ b2,
                                                     const float* __restrict__ gf,
                                                     const float* __restrict__ bf_,
                                                     unsigned short* __restrict__ out) {
  const int t = threadIdx.x, lane = t & 63, wv = t >> 6;
  const int row = blockIdx.x * 4 + wv;
  const float* p = t2 + (long)row * 512 + lane * 8;
  f32x4 a = *(const f32x4*)p;
  f32x4 c = *(const f32x4*)(p + 4);
  const float s0 = S[2 * row], q0 = S[2 * row + 1];
  const float m1 = s0 * (1.f / 512.f);
  const float i1 = rsqrtf(q0 * (1.f / 512.f) - m1 * m1 + 1e-5f);
  float v[8];
  const float* g2p = g2 + lane * 8;
  const float* b2p = b2 + lane * 8;
#pragma unroll
  for (int j = 0; j < 4; ++j) v[j] = (a[j] - m1) * i1 * g2p[j] + b2p[j];
#pragma unroll
  for (int j = 0; j < 4; ++j) v[4 + j] = (c[j] - m1) * i1 * g2p[4 + j] + b2p[4 + j];
  float s = 0.f, q = 0.f;
#pragma unroll
  for (int j = 0; j < 8; ++j) { s += v[j]; q += v[j] * v[j]; }
#pragma unroll
  for (int msk = 32; msk; msk >>= 1) { s += __shfl_xor(s, msk, 64); q += __shfl_xor(q, msk, 64); }
  const float m2 = s * (1.f / 512.f);
  const float i2 = rsqrtf(q * (1.f / 512.f) - m2 * m2 + 1e-5f);
  const float* gfp = gf + lane * 8;
  const float* bfp = bf_ + lane * 8;
  u16x8 o;
#pragma unroll
  for (int j = 0; j < 8; ++j) o[j] = f2bf((v[j] - m2) * i2 * gfp[j] + bfp[j]);
  *(u16x8*)(out + (long)row * 512 + lane * 8) = o;
}

// ---------------------------------------------------------------- phase C (validated)
__global__ __launch_bounds__(256) void phasec_kernel(const float* __restrict__ subp,
                                                     const unsigned short* __restrict__ objbf,
                                                     const float* __restrict__ vsub,
                                                     const float* __restrict__ vobj,
                                                     float* __restrict__ out) {
  constexpr int ABY = 128 * 64 * 2;
  __shared__ __align__(16) char SMEM[67584];
  char* Asb = SMEM;
  char* Bsb = SMEM + 2 * ABY;
  float* Wl = (float*)(SMEM + 4 * ABY);
  const int t = threadIdx.x;
  const int i = blockIdx.x, b = blockIdx.y;
  const long base_bi = ((long)b * 128 + i) * 512;
  for (int d = t; d < 512; d += 256) Wl[d] = vsub[base_bi + d] * vobj[base_bi + d];

  const int lane = t & 63, wv = t >> 6;
  const int wr = wv >> 1, wc = wv & 1;
  f32x4 acc[4][4] = {};

  int row[4], slot[4];
#pragma unroll
  for (int c = 0; c < 4; ++c) { int id = c * 256 + t; row[c] = id >> 3; slot[c] = id & 7; }

  f32x4 fa[4][2];
  u16x8 rb[4];
  auto load = [&](int kt) {
#pragma unroll
    for (int c = 0; c < 4; ++c) {
      const long g = ((long)b * 128 + row[c]) * 512 + kt + slot[c] * 8;
      fa[c][0] = *(const f32x4*)(subp + g);
      fa[c][1] = *(const f32x4*)(subp + g + 4);
      rb[c] = *(const u16x8*)(objbf + g);
    }
  };
  auto store = [&](int cur, int ktd) {
#pragma unroll
    for (int c = 0; c < 4; ++c) {
      const float* wp = Wl + ktd + slot[c] * 8;
      f32x4 w0 = *(const f32x4*)wp;
      f32x4 w1 = *(const f32x4*)(wp + 4);
      u16x8 oa;
      oa[0] = f2bf(fa[c][0][0] * w0[0]); oa[1] = f2bf(fa[c][0][1] * w0[1]);
      oa[2] = f2bf(fa[c][0][2] * w0[2]); oa[3] = f2bf(fa[c][0][3] * w0[3]);
      oa[4] = f2bf(fa[c][1][0] * w1[0]); oa[5] = f2bf(fa[c][1][1] * w1[1]);
      oa[6] = f2bf(fa[c][1][2] * w1[2]); oa[7] = f2bf(fa[c][1][3] * w1[3]);
      *(u16x8*)(Asb + cur * ABY + swz(row[c], slot[c] * 16)) = oa;
      *(u16x8*)(Bsb + cur * ABY + swz(row[c], slot[c] * 16)) = rb[c];
    }
  };

  __syncthreads();
  load(0);
  store(0, 0);
  load(64);
  __syncthreads();
  for (int ki = 0; ki < 8; ++ki) {
    const int cur = ki & 1;
    if (ki + 1 < 8) store(cur ^ 1, (ki + 1) * 64);
    if (ki + 2 < 8) load((ki + 2) * 64);
#pragma unroll
    for (int kk = 0; kk < 2; ++kk) {
      const int kb = kk * 64 + ((lane >> 4) << 4);
      bf16x8 af[4], bfv[4];
#pragma unroll
      for (int mi = 0; mi < 4; ++mi)
        af[mi] = *(const bf16x8*)(Asb + cur * ABY + swz(wr * 64 + mi * 16 + (lane & 15), kb));
#pragma unroll
      for (int ni = 0; ni < 4; ++ni)
        bfv[ni] = *(const bf16x8*)(Bsb + cur * ABY + swz(wc * 64 + ni * 16 + (lane & 15), kb));
#pragma unroll
      for (int mi = 0; mi < 4; ++mi)
#pragma unroll
        for (int ni = 0; ni < 4; ++ni)
          acc[mi][ni] = __builtin_amdgcn_mfma_f32_16x16x32_bf16(af[mi], bfv[ni], acc[mi][ni], 0, 0, 0);
    }
    __syncthreads();
  }
  float* C = (float*)SMEM;
#pragma unroll
  for (int mi = 0; mi < 4; ++mi)
#pragma unroll
    for (int rr = 0; rr < 4; ++rr) {
      const int j = wr * 64 + mi * 16 + ((lane >> 4) << 2) + rr;
      float* crow = C + j * 132 + wc * 64 + (lane & 15);
#pragma unroll
      for (int ni = 0; ni < 4; ++ni) crow[ni * 16] = acc[mi][ni][rr];
    }
  __syncthreads();
  float* ob = out + ((long)b * 128 + i) * 128 * 128;
  const int cc = (t & 31) * 4, jb = (t >> 5) * 16;
#pragma unroll
  for (int q = 0; q < 16; ++q) {
    const int j = jb + q;
    f32x4 v = *(const f32x4*)(C + j * 132 + cc);
    *(f32x4*)(ob + (long)j * 128 + cc) = v;
  }
}

// ---------------------------------------------------------------- launch
extern "C" void kernel_launch(void* const* d_in, const int* in_sizes, int n_in, void* d_out,
                              int out_size, void* d_ws, size_t ws_size, hipStream_t stream) {
  const float* x          = (const float*)d_in[0];
  const float* attn_in_w  = (const float*)d_in[1];
  const float* attn_in_b  = (const float*)d_in[2];
  const float* attn_out_w = (const float*)d_in[3];
  const float* attn_out_b = (const float*)d_in[4];
  const float* ln1_w = (const float*)d_in[5];
  const float* ln1_b = (const float*)d_in[6];
  const float* ln2_w = (const float*)d_in[7];
  const float* ln2_b = (const float*)d_in[8];
  const float* ff1_w = (const float*)d_in[9];
  const float* ff1_b = (const float*)d_in[10];
  const float* ff2_w = (const float*)d_in[11];
  const float* ff2_b = (const float*)d_in[12];
  const float* fln_w = (const float*)d_in[13];
  const float* fln_b = (const float*)d_in[14];
  const float* mlp_w0 = (const float*)d_in[15];
  const float* mlp_b0 = (const float*)d_in[16];
  const float* mlp_w1 = (const float*)d_in[17];
  const float* mlp_b1 = (const float*)d_in[18];
  const float* mlp_w2 = (const float*)d_in[19];
  const float* mlp_b2 = (const float*)d_in[20];
  float* out = (float*)d_out;
  (void)in_sizes; (void)n_in; (void)out_size; (void)ws_size;

  char* ws = (char*)d_ws;
  size_t off = 0;
  auto alloc = [&](size_t bytes) -> void* {
    void* p = (void*)(ws + off);
    off += (bytes + 255) & ~(size_t)255;
    return p;
  };
  float* stats         = (float*)alloc((size_t)6 * 1024 * 2 * 4);
  unsigned short* t1   = (unsigned short*)alloc((size_t)1024 * 2048 * 2);
  float* t2a           = (float*)alloc((size_t)1024 * 512 * 4);
  float* t2b           = (float*)alloc((size_t)1024 * 512 * 4);
  unsigned short* hbfH = (unsigned short*)alloc((size_t)1024 * 512 * 2);
  unsigned short* z1   = (unsigned short*)alloc((size_t)4 * 1024 * 512 * 2);
  unsigned short* z2   = (unsigned short*)alloc((size_t)4 * 1024 * 512 * 2);
  float* hf4           = (float*)alloc((size_t)4 * 1024 * 512 * 4);
  unsigned short* hb4  = (unsigned short*)alloc((size_t)4 * 1024 * 512 * 2);

  hipMemsetAsync(stats, 0, (size_t)6 * 1024 * 2 * 4, stream);

  for (int L = 0; L < 3; ++L) {
    float* Sout = stats + (2 * L) * 2048;
    float* Sff  = stats + (2 * L + 1) * 2048;
    const float* Sprev = stats + (2 * L - 1) * 2048;
    // ---- qkv (W fp32)
    if (L == 0)
      gemm2_kernel<64, 128, 0, 1, 1, 0, 0, 0, 0, 0, 1><<<dim3(12, 16), 256, 0, stream>>>(
          nullptr, x, nullptr, nullptr, nullptr, nullptr, attn_in_w, attn_in_b,
          nullptr, nullptr, nullptr, nullptr, nullptr, t1, nullptr,
          1024, 1536, 512, 0, 0, 0, 0);
    else
      gemm2_kernel<64, 128, 1, 0, 1, 0, 0, 0, 0, 0, 1><<<dim3(12, 16), 256, 0, stream>>>(
          nullptr, t2b, Sprev, ln2_w + (L - 1) * 512, ln2_b + (L - 1) * 512,
          nullptr, attn_in_w + (long)L * 1536 * 512, attn_in_b + L * 1536,
          nullptr, nullptr, nullptr, nullptr, nullptr, t1, nullptr,
          1024, 1536, 512, 0, 0, 0, 0);
    // ---- attention + outproj + residual (+stats, plain stores)
    if (L == 0)
      attnop_kernel<0><<<128, 512, 0, stream>>>(
          t1, attn_out_w, attn_out_b, x, nullptr, nullptr, nullptr, t2a, Sout);
    else
      attnop_kernel<1><<<128, 512, 0, stream>>>(
          t1, attn_out_w + (long)L * 512 * 512, attn_out_b + L * 512, t2b,
          Sprev, ln2_w + (L - 1) * 512, ln2_b + (L - 1) * 512, t2a, Sout);
    // ---- ff1 (LN1 on load, relu, W fp32)
    gemm2_kernel<64, 128, 1, 0, 1, 0, 0, 1, 0, 0, 1><<<dim3(16, 16), 256, 0, stream>>>(
        nullptr, t2a, Sout, ln1_w + L * 512, ln1_b + L * 512,
        nullptr, ff1_w + (long)L * 2048 * 512, ff1_b + L * 2048,
        nullptr, nullptr, nullptr, nullptr, nullptr, t1, nullptr,
        1024, 2048, 512, 0, 0, 0, 0);
    // ---- ff2 + residual LN1(t2a) (+stats atomics, W fp32)
    gemm2_kernel<32, 64, 0, 0, 1, 1, 1, 0, 1, 1, 0><<<dim3(8, 32), 256, 0, stream>>>(
        t1, nullptr, nullptr, nullptr, nullptr,
        nullptr, ff2_w + (long)L * 512 * 2048, ff2_b + L * 512,
        t2a, Sout, ln1_w + L * 512, ln1_b + L * 512,
        t2b, nullptr, Sff, 1024, 512, 2048, 0, 0, 0, 0);
  }
  // ---- last LN2 -> final LN
  lastln_kernel<<<256, 256, 0, stream>>>(t2b, stats + 5 * 2048, ln2_w + 2 * 512, ln2_b + 2 * 512,
                                         fln_w, fln_b, hbfH);
  // ---- head MLPs (z = 4 heads, W fp32)
  gemm2_kernel<64, 128, 0, 0, 1, 0, 0, 1, 0, 0, 1><<<dim3(4, 16, 4), 256, 0, stream>>>(
      hbfH, nullptr, nullptr, nullptr, nullptr, nullptr, mlp_w0, mlp_b0,
      nullptr, nullptr, nullptr, nullptr, nullptr, z1, nullptr,
      1024, 512, 512, 0, 512 * 512, 512, 1024 * 512);
  gemm2_kernel<64, 128, 0, 0, 1, 0, 0, 1, 0, 0, 1><<<dim3(4, 16, 4), 256, 0, stream>>>(
      z1, nullptr, nullptr, nullptr, nullptr, nullptr, mlp_w1, mlp_b1,
      nullptr, nullptr, nullptr, nullptr, nullptr, z2, nullptr,
      1024, 512, 512, 1024 * 512, 512 * 512, 512, 1024 * 512);
  gemm2_kernel<64, 128, 0, 0, 1, 0, 0, 0, 0, 1, 1><<<dim3(4, 16, 4), 256, 0, stream>>>(
      z2, nullptr, nullptr, nullptr, nullptr, nullptr, mlp_w2, mlp_b2,
      nullptr, nullptr, nullptr, nullptr, hf4, hb4, nullptr,
      1024, 512, 512, 1024 * 512, 512 * 512, 512, 1024 * 512);

  // heads: 0=sub, 1=obj, 2=verb_sub, 3=verb_obj
  phasec_kernel<<<dim3(128, 8), 256, 0, stream>>>(
      hf4, hb4 + 1 * 1024 * 512, hf4 + 2L * 1024 * 512, hf4 + 3L * 1024 * 512, out);
}